// Round 12
// baseline (176.462 us; speedup 1.0000x reference)
//
#include <hip/hip_runtime.h>
#include <hip/hip_fp16.h>

// SSIM loss, fused producer/consumer, LDS-lean occupancy build.
// (16,3,512,512) f32 -> scalar. Box = separable 11-tap mean, zero pad.
// Block = (plane, 64x64 tile), 128 threads = 2 waves:
//   wave 0: H producer — 8 rows/batch x 8 runs x 8 cols -> fp16 ring (b128 stores)
//   wave 1: V consumer — 1 col each; running vertical sums; 11-lag subtraction
//           re-read from the ring (NO register arrays -> no spill, per R6/R11).
// Ring: CAP=27 slots x 164 dwords {q0q1[64] | q2q3[64] | q4 packed pairs[32] | pad 4}
//   = 17.7 KB LDS -> 9 blocks/CU = 18 waves/CU supply (R5 was capped at 12).
// SSTR=164 = 4 (mod 32): producer uint4 (ds_write_b128) stores cover all 32
//   banks exactly evenly (8 dwords/bank per wave-instr) -> conflict-free by
//   construction. Consumer reads are stride-1 b32 (2-way = free) and
//   pair-broadcast for q4.

#define CAP   27
#define SSTR  164
#define P1    64
#define P2    128
#define C1K   1.4641f            // 0.01^2 * 121^2
#define C2K   13.1769f           // 0.03^2 * 121^2

__device__ __forceinline__ unsigned int h2bits(float a, float b) {
    const __half2 h = __floats2half2_rn(a, b);
    return *(const unsigned int*)&h;
}

__launch_bounds__(128, 3)
__global__ void ssim_fused(const float* __restrict__ img1,
                           const float* __restrict__ img2,
                           float* __restrict__ out)
{
    __shared__ unsigned int ring[CAP * SSTR];   // 17712 B

    const int x0 = blockIdx.x * 64;
    const int y0 = blockIdx.y * 64;
    const size_t pbase = (size_t)blockIdx.z * (512 * 512);
    const int tid = threadIdx.x;

    const int hj = (tid & 63) >> 3;     // producer: row in batch (0..7)
    const int hk = tid & 7;             // producer: run (8 cols each)
    const int xl = x0 + hk * 8 - 8;     // f4-aligned load start
    const int col = tid & 63;           // consumer: column

    float S0 = 0.f, S1 = 0.f, S2 = 0.f, S3 = 0.f, S4 = 0.f, accs = 0.f;
    int pslot = hj;                     // (8t+hj) % 27, maintained incrementally
    int cbase = 0;                      // slot of rel = 8*(t-1)

    for (int t = 0; t <= 10; ++t) {
        if (tid < 64) {
            // ---------------- producer: batch t (rels 8t..8t+7) -------------
            if (t <= 9) {
                const int rel = 8 * t + hj;
                if (rel <= 73) {
                    const int r = y0 - 5 + rel;
                    float a[24], b[24];
                    if ((unsigned)r < 512u) {
                        const float* p1 = img1 + pbase + (size_t)r * 512;
                        const float* p2 = img2 + pbase + (size_t)r * 512;
#pragma unroll
                        for (int u = 0; u < 6; ++u) {
                            const int c4 = xl + 4 * u;
                            float4 v1 = {0.f, 0.f, 0.f, 0.f};
                            float4 v2 = {0.f, 0.f, 0.f, 0.f};
                            if ((unsigned)c4 < 512u) {
                                v1 = *(const float4*)(p1 + c4);
                                v2 = *(const float4*)(p2 + c4);
                            }
                            a[4*u]=v1.x; a[4*u+1]=v1.y; a[4*u+2]=v1.z; a[4*u+3]=v1.w;
                            b[4*u]=v2.x; b[4*u+1]=v2.y; b[4*u+2]=v2.z; b[4*u+3]=v2.w;
                        }
                    } else {
#pragma unroll
                        for (int u = 0; u < 24; ++u) { a[u] = 0.f; b[u] = 0.f; }
                    }

                    // initial 11-window: output col hk*8 covers a[3..13]
                    float w0=0.f, w1=0.f, w2=0.f, w3=0.f, w4=0.f;
#pragma unroll
                    for (int c = 0; c < 11; ++c) {
                        const float av = a[c+3], bv = b[c+3];
                        w0 += av; w1 += bv; w2 += av*av; w3 += bv*bv; w4 += av*bv;
                    }

                    // buffer 8 cols (static idx), then explicit b128 stores
                    unsigned int u01[8], u23[8], u4p[4];
                    float w4e = 0.f;
#pragma unroll
                    for (int i = 0; i < 8; ++i) {
                        u01[i] = h2bits(w0, w1);
                        u23[i] = h2bits(w2, w3);
                        if ((i & 1) == 0) w4e = w4;
                        else u4p[i >> 1] = h2bits(w4e, w4);  // (even col, odd col)
                        if (i < 7) {   // slide: add a[14+i], drop a[3+i]
                            const float aN=a[14+i], aO=a[3+i];
                            const float bN=b[14+i], bO=b[3+i];
                            w0 += aN - aO;
                            w1 += bN - bO;
                            w2 += aN*aN - aO*aO;
                            w3 += bN*bN - bO*bO;
                            w4 += aN*bN - aO*bO;
                        }
                    }

                    unsigned int* rb = &ring[pslot * SSTR];
                    *(uint4*)&rb[hk * 8]          = make_uint4(u01[0],u01[1],u01[2],u01[3]);
                    *(uint4*)&rb[hk * 8 + 4]      = make_uint4(u01[4],u01[5],u01[6],u01[7]);
                    *(uint4*)&rb[P1 + hk * 8]     = make_uint4(u23[0],u23[1],u23[2],u23[3]);
                    *(uint4*)&rb[P1 + hk * 8 + 4] = make_uint4(u23[4],u23[5],u23[6],u23[7]);
                    *(uint4*)&rb[P2 + hk * 4]     = make_uint4(u4p[0],u4p[1],u4p[2],u4p[3]);
                }
                pslot += 8; if (pslot >= CAP) pslot -= CAP;
            }
        } else {
            // ---------------- consumer: batch t-1 (rels 8(t-1)..+7) ---------
            if (t >= 1) {
                const int relbase = 8 * (t - 1);
#pragma unroll
                for (int jj = 0; jj < 8; ++jj) {
                    const int rel = relbase + jj;
                    if (rel <= 73) {   // uniform guard, unroll-safe
                        int sa = cbase + jj; if (sa >= CAP) sa -= CAP;
                        const unsigned int* ab = &ring[sa * SSTR];
                        const unsigned int u01 = ab[col];
                        const unsigned int u23 = ab[P1 + col];
                        const unsigned int u4  = ab[P2 + (col >> 1)];
                        const float2 f01 = __half22float2(*(const __half2*)&u01);
                        const float2 f23 = __half22float2(*(const __half2*)&u23);
                        const float2 f4v = __half22float2(*(const __half2*)&u4);
                        const float q4a = (col & 1) ? f4v.y : f4v.x;
                        S0 += f01.x; S1 += f01.y; S2 += f23.x; S3 += f23.y; S4 += q4a;
                        if (rel >= 11) {
                            int ss = sa - 11; if (ss < 0) ss += CAP;
                            const unsigned int* sb = &ring[ss * SSTR];
                            const unsigned int v01 = sb[col];
                            const unsigned int v23 = sb[P1 + col];
                            const unsigned int v4  = sb[P2 + (col >> 1)];
                            const float2 g01 = __half22float2(*(const __half2*)&v01);
                            const float2 g23 = __half22float2(*(const __half2*)&v23);
                            const float2 g4v = __half22float2(*(const __half2*)&v4);
                            const float q4s = (col & 1) ? g4v.y : g4v.x;
                            S0 -= g01.x; S1 -= g01.y; S2 -= g23.x; S3 -= g23.y; S4 -= q4s;
                        }
                        if (rel >= 10) {
                            // SSIM on raw sums; 121^4 cancels in num/den.
                            const float t01 = S0 * S1;
                            const float p0 = S0 * S0, p1 = S1 * S1;
                            const float num = (2.f * t01 + C1K)
                                            * (2.f * (121.f * S4 - t01) + C2K);
                            const float den = (p0 + p1 + C1K)
                                            * (121.f * (S2 + S3) - p0 - p1 + C2K);
                            accs += num * __builtin_amdgcn_rcpf(den);
                        }
                    }
                }
                cbase += 8; if (cbase >= CAP) cbase -= CAP;
            }
        }
        __syncthreads();
    }

    // ---------------- block reduction + global atomic ----------------
    float tot = accs;
#pragma unroll
    for (int off = 32; off > 0; off >>= 1)
        tot += __shfl_down(tot, off);
    float* red = (float*)ring;
    if ((tid & 63) == 0) red[tid >> 6] = tot;
    __syncthreads();
    if (tid == 0) {
        const float s = red[0] + red[1];
        atomicAdd(out, 1.0f / 3072.0f - s * (1.0f / 12582912.0f));
    }
}

extern "C" void kernel_launch(void* const* d_in, const int* in_sizes, int n_in,
                              void* d_out, int out_size, void* d_ws, size_t ws_size,
                              hipStream_t stream)
{
    const float* img1 = (const float*)d_in[0];
    const float* img2 = (const float*)d_in[1];
    float* out = (float*)d_out;

    hipMemsetAsync(out, 0, sizeof(float), stream);

    dim3 grid(8, 8, 48);
    ssim_fused<<<grid, dim3(128), 0, stream>>>(img1, img2, out);
}